// Round 1
// baseline (548.920 us; speedup 1.0000x reference)
//
#include <hip/hip_runtime.h>
#include <stdint.h>

#define B_ 2
#define N_ 2048
#define C_ 512
#define H_ 8
#define D_ 64
#define TOPK_ 100
#define BN_ (B_*N_)

__device__ __forceinline__ int mbcnt64(unsigned long long m) {
  return __builtin_amdgcn_mbcnt_hi((unsigned)(m >> 32),
         __builtin_amdgcn_mbcnt_lo((unsigned)m, 0u));
}

// out = X @ W^T + bias ; X:[M][512], W:[512][512] row-major W[c][k].
// blockIdx.z selects among up to 3 independent (X,W,b,O) problems.
// scatter=1: write head layout O[((b*H+h)*N+n)*64 + d] with h=blockIdx.y.
__global__ __launch_bounds__(256)
void gemm_xwt(const float* __restrict__ X0, const float* __restrict__ X1, const float* __restrict__ X2,
              const float* __restrict__ W0, const float* __restrict__ W1, const float* __restrict__ W2,
              const float* __restrict__ b0, const float* __restrict__ b1, const float* __restrict__ b2,
              float* __restrict__ O0, float* __restrict__ O1, float* __restrict__ O2,
              int scatter)
{
  int z = blockIdx.z;
  const float* X = (z == 0) ? X0 : ((z == 1) ? X1 : X2);
  const float* W = (z == 0) ? W0 : ((z == 1) ? W1 : W2);
  const float* bs = (z == 0) ? b0 : ((z == 1) ? b1 : b2);
  float* O = (z == 0) ? O0 : ((z == 1) ? O1 : O2);

  __shared__ float Xs[32][72];   // [k][m], padded
  __shared__ float Ws[32][72];   // [k][c]

  int t = threadIdx.x;
  int tr = t >> 4, tc = t & 15;
  int m0 = blockIdx.x * 64, c0 = blockIdx.y * 64;

  float acc[4][4] = {};

  for (int k0 = 0; k0 < C_; k0 += 32) {
    #pragma unroll
    for (int j2 = 0; j2 < 2; ++j2) {
      int fid = t + j2 * 256;        // 0..511
      int row = fid & 63;            // lane-fast over rows -> conflict-free LDS writes
      int dk  = (fid >> 6) << 2;     // 0..28
      float4 xv = *(const float4*)(X + (size_t)(m0 + row) * C_ + k0 + dk);
      Xs[dk+0][row] = xv.x; Xs[dk+1][row] = xv.y; Xs[dk+2][row] = xv.z; Xs[dk+3][row] = xv.w;
      float4 wv = *(const float4*)(W + (size_t)(c0 + row) * C_ + k0 + dk);
      Ws[dk+0][row] = wv.x; Ws[dk+1][row] = wv.y; Ws[dk+2][row] = wv.z; Ws[dk+3][row] = wv.w;
    }
    __syncthreads();
    #pragma unroll
    for (int k = 0; k < 32; ++k) {
      float4 a = *(const float4*)&Xs[k][tr << 2];
      float4 b = *(const float4*)&Ws[k][tc << 2];
      float ar[4] = {a.x, a.y, a.z, a.w};
      float br[4] = {b.x, b.y, b.z, b.w};
      #pragma unroll
      for (int i = 0; i < 4; ++i)
        #pragma unroll
        for (int j = 0; j < 4; ++j)
          acc[i][j] = fmaf(ar[i], br[j], acc[i][j]);
    }
    __syncthreads();
  }

  float bv[4];
  #pragma unroll
  for (int j = 0; j < 4; ++j) bv[j] = bs[c0 + (tc << 2) + j];

  #pragma unroll
  for (int i = 0; i < 4; ++i) {
    float4 o = make_float4(acc[i][0] + bv[0], acc[i][1] + bv[1],
                           acc[i][2] + bv[2], acc[i][3] + bv[3]);
    int m = m0 + (tr << 2) + i;
    if (scatter) {
      int b = m >> 11;           // /N_
      int n = m & (N_ - 1);
      float* dst = O + ((size_t)(b * H_ + blockIdx.y) * N_ + n) * D_ + (tc << 2);
      *(float4*)dst = o;
    } else {
      *(float4*)(O + (size_t)m * C_ + c0 + (tc << 2)) = o;
    }
  }
}

// S[n][m] = scale * dot(qh[slice][n][:], kh[slice][m][:]) per slice (b,h)
__global__ __launch_bounds__(256)
void qk_gemm(const float* __restrict__ qh, const float* __restrict__ kh,
             float* __restrict__ S, int slice0)
{
  __shared__ float Qs[64][72];   // [k][n]
  __shared__ float Ks[64][72];   // [k][m]

  int s_local = blockIdx.z;
  int slice = slice0 + s_local;
  const float* Q = qh + (size_t)slice * N_ * D_;
  const float* K = kh + (size_t)slice * N_ * D_;
  float* Sp = S + (size_t)s_local * N_ * N_;

  int t = threadIdx.x;
  int tr = t >> 4, tc = t & 15;
  int n0 = blockIdx.y * 64, m0 = blockIdx.x * 64;

  #pragma unroll
  for (int j2 = 0; j2 < 4; ++j2) {
    int fid = t + j2 * 256;        // 0..1023
    int row = fid & 63;
    int dk  = (fid >> 6) << 2;     // 0..60
    float4 qv = *(const float4*)(Q + (size_t)(n0 + row) * D_ + dk);
    Qs[dk+0][row] = qv.x; Qs[dk+1][row] = qv.y; Qs[dk+2][row] = qv.z; Qs[dk+3][row] = qv.w;
    float4 kv = *(const float4*)(K + (size_t)(m0 + row) * D_ + dk);
    Ks[dk+0][row] = kv.x; Ks[dk+1][row] = kv.y; Ks[dk+2][row] = kv.z; Ks[dk+3][row] = kv.w;
  }
  __syncthreads();

  float acc[4][4] = {};
  #pragma unroll
  for (int k = 0; k < 64; ++k) {
    float4 a = *(const float4*)&Qs[k][tr << 2];
    float4 b = *(const float4*)&Ks[k][tc << 2];
    float ar[4] = {a.x, a.y, a.z, a.w};
    float br[4] = {b.x, b.y, b.z, b.w};
    #pragma unroll
    for (int i = 0; i < 4; ++i)
      #pragma unroll
      for (int j = 0; j < 4; ++j)
        acc[i][j] = fmaf(ar[i], br[j], acc[i][j]);
  }

  const float scale = 0.125f;  // D^-0.5
  #pragma unroll
  for (int i = 0; i < 4; ++i) {
    float4 o = make_float4(acc[i][0] * scale, acc[i][1] * scale,
                           acc[i][2] * scale, acc[i][3] * scale);
    *(float4*)(Sp + (size_t)(n0 + (tr << 2) + i) * N_ + m0 + (tc << 2)) = o;
  }
}

// One wave per attention row: exact 100th-largest radix select -> softmax over
// kept -> compact (idx,w) to LDS -> gather-PV -> write pre-projection out.
__global__ __launch_bounds__(256)
void topk_softmax_pv(const float* __restrict__ S, const float* __restrict__ vh,
                     float* __restrict__ outp, int slice0)
{
  __shared__ float wL[4][2048];
  __shared__ unsigned short iL[4][2048];

  int t = threadIdx.x;
  int wv = t >> 6;
  int lane = t & 63;
  int gr = blockIdx.x * 4 + wv;        // chunk-local row id
  int s_local = gr >> 11;              // /2048
  int row = gr & (N_ - 1);
  int slice = slice0 + s_local;

  const float* Srow = S + (size_t)s_local * N_ * N_ + (size_t)row * N_;

  // load 2048 logits: 32 per lane; value (i,c) on lane l <-> col i*256 + l*4 + c
  float x[32];
  #pragma unroll
  for (int i = 0; i < 8; ++i) {
    float4 v = *(const float4*)(Srow + i * 256 + lane * 4);
    x[i*4+0] = v.x; x[i*4+1] = v.y; x[i*4+2] = v.z; x[i*4+3] = v.w;
  }
  // order-preserving float -> uint transform
  unsigned u[32];
  #pragma unroll
  for (int i = 0; i < 32; ++i) {
    unsigned bits = __float_as_uint(x[i]);
    u[i] = bits ^ ((unsigned)(((int)bits) >> 31) | 0x80000000u);
  }

  // radix select: max t with count(u >= t) >= TOPK  == 100th largest value
  unsigned thr = 0u;
  for (int bit = 31; bit >= 0; --bit) {
    unsigned cand = thr | (1u << bit);
    int cnt = 0;
    #pragma unroll
    for (int i = 0; i < 32; ++i) {
      unsigned long long m = __ballot(u[i] >= cand);
      cnt += __popcll(m);
    }
    if (cnt >= TOPK_) thr = cand;
  }

  // row max (top-1 is always kept)
  float mx = -1e30f;
  #pragma unroll
  for (int i = 0; i < 32; ++i) mx = fmaxf(mx, x[i]);
  #pragma unroll
  for (int off = 32; off >= 1; off >>= 1) mx = fmaxf(mx, __shfl_xor(mx, off));

  // sum of exp over kept
  float s = 0.f;
  #pragma unroll
  for (int i = 0; i < 32; ++i) {
    bool kp = (u[i] >= thr);
    float ev = kp ? __expf(x[i] - mx) : 0.f;
    s += ev;
  }
  #pragma unroll
  for (int off = 32; off >= 1; off >>= 1) s += __shfl_xor(s, off);
  float inv = 1.f / s;

  // ballot-compaction of kept entries (deterministic order)
  int base = 0;
  #pragma unroll
  for (int i = 0; i < 32; ++i) {
    bool kp = (u[i] >= thr);
    unsigned long long m = __ballot(kp);
    if (kp) {
      int pos = base + mbcnt64(m);
      wL[wv][pos] = __expf(x[i] - mx) * inv;
      iL[wv][pos] = (unsigned short)((i >> 2) * 256 + lane * 4 + (i & 3));
    }
    base += __popcll(m);
  }
  int total = base;

  // gather-PV: lane = output dim d
  const float* Vs = vh + (size_t)slice * N_ * D_;
  float acc = 0.f;
  int e2 = 0;
  for (; e2 + 4 <= total; e2 += 4) {
    float w0 = wL[wv][e2+0], w1 = wL[wv][e2+1], w2 = wL[wv][e2+2], w3 = wL[wv][e2+3];
    int j0 = iL[wv][e2+0], j1 = iL[wv][e2+1], j2 = iL[wv][e2+2], j3 = iL[wv][e2+3];
    acc = fmaf(w0, Vs[(size_t)j0 * D_ + lane], acc);
    acc = fmaf(w1, Vs[(size_t)j1 * D_ + lane], acc);
    acc = fmaf(w2, Vs[(size_t)j2 * D_ + lane], acc);
    acc = fmaf(w3, Vs[(size_t)j3 * D_ + lane], acc);
  }
  for (; e2 < total; ++e2) {
    acc = fmaf(wL[wv][e2], Vs[(size_t)iL[wv][e2] * D_ + lane], acc);
  }

  int b = slice >> 3;   // /H_
  int h = slice & 7;
  outp[((size_t)(b * N_ + row)) * C_ + h * D_ + lane] = acc;
}

extern "C" void kernel_launch(void* const* d_in, const int* in_sizes, int n_in,
                              void* d_out, int out_size, void* d_ws, size_t ws_size,
                              hipStream_t stream) {
  const float* q  = (const float*)d_in[0];
  const float* k  = (const float*)d_in[1];
  const float* v  = (const float*)d_in[2];
  const float* Wq = (const float*)d_in[3];
  const float* bq = (const float*)d_in[4];
  const float* Wk = (const float*)d_in[5];
  const float* bk = (const float*)d_in[6];
  const float* Wv = (const float*)d_in[7];
  const float* bv = (const float*)d_in[8];
  const float* Wp = (const float*)d_in[9];
  const float* bp = (const float*)d_in[10];

  const size_t NB = (size_t)B_ * H_ * N_ * D_;   // 2,097,152 floats
  float* qh  = (float*)d_ws;
  float* kh  = qh + NB;
  float* vh  = kh + NB;
  float* pre = vh + NB;      // [BN][C] pre-projection attention output
  float* S   = pre + NB;     // chunked logits

  size_t fixedBytes = 4 * NB * sizeof(float);                 // 32 MB
  size_t sliceBytes = (size_t)N_ * N_ * sizeof(float);        // 16.8 MB
  int ns = 1;
  if (ws_size > fixedBytes + sliceBytes) {
    size_t a = (ws_size - fixedBytes) / sliceBytes;
    ns = (a > 16) ? 16 : (int)a;
  }

  dim3 blk(256);

  // Q/K/V projections (one launch, z selects)
  gemm_xwt<<<dim3(BN_/64, C_/64, 3), blk, 0, stream>>>(
      q, k, v, Wq, Wk, Wv, bq, bk, bv, qh, kh, vh, 1);

  for (int s0 = 0; s0 < B_ * H_; s0 += ns) {
    int cur = (B_ * H_ - s0) < ns ? (B_ * H_ - s0) : ns;
    qk_gemm<<<dim3(N_/64, N_/64, cur), blk, 0, stream>>>(qh, kh, S, s0);
    topk_softmax_pv<<<dim3(cur * (N_/4)), blk, 0, stream>>>(S, vh, pre, s0);
  }

  // final projection -> d_out
  gemm_xwt<<<dim3(BN_/64, C_/64, 1), blk, 0, stream>>>(
      pre, pre, pre, Wp, Wp, Wp, bp, bp, bp,
      (float*)d_out, (float*)d_out, (float*)d_out, 0);
}

// Round 2
// 544.016 us; speedup vs baseline: 1.0090x; 1.0090x over previous
//
#include <hip/hip_runtime.h>
#include <stdint.h>

#define B_ 2
#define N_ 2048
#define C_ 512
#define H_ 8
#define D_ 64
#define TOPK_ 100
#define BN_ (B_*N_)
#define CAP_ 512   // compaction capacity per row (kept count is ~100-101; cap guards ties)

__device__ __forceinline__ int mbcnt64(unsigned long long m) {
  return __builtin_amdgcn_mbcnt_hi((unsigned)(m >> 32),
         __builtin_amdgcn_mbcnt_lo((unsigned)m, 0u));
}

// ---- 128x128-tile f32 GEMM: O = X @ W^T + bias ----
// X:[M][K] row-major, W:[Nc][K] row-major. blockIdx.z selects problem.
// scatter=1: write head layout O[((b*H+h)*N+n)*64 + d].
__global__ __launch_bounds__(256)
void proj3(const float* __restrict__ X0, const float* __restrict__ X1, const float* __restrict__ X2,
           const float* __restrict__ W0, const float* __restrict__ W1, const float* __restrict__ W2,
           const float* __restrict__ b0, const float* __restrict__ b1, const float* __restrict__ b2,
           float* __restrict__ O0, float* __restrict__ O1, float* __restrict__ O2,
           int K, int scatter)
{
  int z = blockIdx.z;
  const float* X = (z == 0) ? X0 : ((z == 1) ? X1 : X2);
  const float* W = (z == 0) ? W0 : ((z == 1) ? W1 : W2);
  const float* bs = (z == 0) ? b0 : ((z == 1) ? b1 : b2);
  float* O = (z == 0) ? O0 : ((z == 1) ? O1 : O2);

  __shared__ float Xs[32][132];   // [k][m]
  __shared__ float Ws[32][132];   // [k][c]

  int t = threadIdx.x;
  int tr = t >> 4, tc = t & 15;
  int m0 = blockIdx.x * 128, c0 = blockIdx.y * 128;

  float acc[8][8] = {};

  for (int k0 = 0; k0 < K; k0 += 32) {
    #pragma unroll
    for (int j2 = 0; j2 < 4; ++j2) {
      int fid = t + j2 * 256;      // 0..1023
      int row = fid >> 3;          // 0..127  (8 lanes per row -> 128B coalesced)
      int dk  = (fid & 7) << 2;    // 0..28
      float4 xv = *(const float4*)(X + (size_t)(m0 + row) * K + k0 + dk);
      Xs[dk+0][row] = xv.x; Xs[dk+1][row] = xv.y; Xs[dk+2][row] = xv.z; Xs[dk+3][row] = xv.w;
      float4 wv = *(const float4*)(W + (size_t)(c0 + row) * K + k0 + dk);
      Ws[dk+0][row] = wv.x; Ws[dk+1][row] = wv.y; Ws[dk+2][row] = wv.z; Ws[dk+3][row] = wv.w;
    }
    __syncthreads();
    #pragma unroll
    for (int k = 0; k < 32; ++k) {
      float a[8], b[8];
      *(float4*)&a[0] = *(const float4*)&Xs[k][(tr << 3) + 0];
      *(float4*)&a[4] = *(const float4*)&Xs[k][(tr << 3) + 4];
      *(float4*)&b[0] = *(const float4*)&Ws[k][(tc << 3) + 0];
      *(float4*)&b[4] = *(const float4*)&Ws[k][(tc << 3) + 4];
      #pragma unroll
      for (int i = 0; i < 8; ++i)
        #pragma unroll
        for (int j = 0; j < 8; ++j)
          acc[i][j] = fmaf(a[i], b[j], acc[i][j]);
    }
    __syncthreads();
  }

  float bv[8];
  #pragma unroll
  for (int j = 0; j < 8; ++j) bv[j] = bs[c0 + (tc << 3) + j];

  #pragma unroll
  for (int i = 0; i < 8; ++i) {
    int m = m0 + (tr << 3) + i;
    #pragma unroll
    for (int j4 = 0; j4 < 8; j4 += 4) {
      float4 o = make_float4(acc[i][j4+0] + bv[j4+0], acc[i][j4+1] + bv[j4+1],
                             acc[i][j4+2] + bv[j4+2], acc[i][j4+3] + bv[j4+3]);
      if (scatter) {
        int b = m >> 11;           // /N_
        int n = m & (N_ - 1);
        int c = c0 + (tc << 3) + j4;
        int h = c >> 6, d = c & 63;
        *(float4*)(O + ((size_t)(b * H_ + h) * N_ + n) * D_ + d) = o;
      } else {
        *(float4*)(O + (size_t)m * C_ + c0 + (tc << 3) + j4) = o;
      }
    }
  }
}

// ---- QK^T per slice: S[n][m] = scale * dot(qh[n], kh[m]), 128x128 tile ----
__global__ __launch_bounds__(256)
void qk128(const float* __restrict__ qh, const float* __restrict__ kh,
           float* __restrict__ S, int slice0)
{
  __shared__ float Qs[32][132];   // [k][n]
  __shared__ float Ks[32][132];   // [k][m]

  int s_local = blockIdx.z;
  int slice = slice0 + s_local;
  const float* Q = qh + (size_t)slice * N_ * D_;
  const float* K = kh + (size_t)slice * N_ * D_;
  float* Sp = S + (size_t)s_local * N_ * N_;

  int t = threadIdx.x;
  int tr = t >> 4, tc = t & 15;
  int n0 = blockIdx.x * 128, m0 = blockIdx.y * 128;

  float acc[8][8] = {};

  for (int k0 = 0; k0 < D_; k0 += 32) {
    #pragma unroll
    for (int j2 = 0; j2 < 4; ++j2) {
      int fid = t + j2 * 256;
      int row = fid >> 3;
      int dk  = (fid & 7) << 2;
      float4 qv = *(const float4*)(Q + (size_t)(n0 + row) * D_ + k0 + dk);
      Qs[dk+0][row] = qv.x; Qs[dk+1][row] = qv.y; Qs[dk+2][row] = qv.z; Qs[dk+3][row] = qv.w;
      float4 kv = *(const float4*)(K + (size_t)(m0 + row) * D_ + k0 + dk);
      Ks[dk+0][row] = kv.x; Ks[dk+1][row] = kv.y; Ks[dk+2][row] = kv.z; Ks[dk+3][row] = kv.w;
    }
    __syncthreads();
    #pragma unroll
    for (int k = 0; k < 32; ++k) {
      float a[8], b[8];
      *(float4*)&a[0] = *(const float4*)&Qs[k][(tr << 3) + 0];
      *(float4*)&a[4] = *(const float4*)&Qs[k][(tr << 3) + 4];
      *(float4*)&b[0] = *(const float4*)&Ks[k][(tc << 3) + 0];
      *(float4*)&b[4] = *(const float4*)&Ks[k][(tc << 3) + 4];
      #pragma unroll
      for (int i = 0; i < 8; ++i)
        #pragma unroll
        for (int j = 0; j < 8; ++j)
          acc[i][j] = fmaf(a[i], b[j], acc[i][j]);
    }
    __syncthreads();
  }

  const float scale = 0.125f;  // D^-0.5
  #pragma unroll
  for (int i = 0; i < 8; ++i) {
    int n = n0 + (tr << 3) + i;
    #pragma unroll
    for (int j4 = 0; j4 < 8; j4 += 4) {
      float4 o = make_float4(acc[i][j4+0] * scale, acc[i][j4+1] * scale,
                             acc[i][j4+2] * scale, acc[i][j4+3] * scale);
      *(float4*)(Sp + (size_t)n * N_ + m0 + (tc << 3) + j4) = o;
    }
  }
}

// ---- one wave per row: exact radix-select of 100th largest -> softmax over
// kept -> compaction -> gather-PV ----
__global__ __launch_bounds__(256)
void topk_softmax_pv(const float* __restrict__ S, const float* __restrict__ vh,
                     float* __restrict__ outp, int slice0)
{
  __shared__ float wL[4][CAP_];
  __shared__ unsigned short iL[4][CAP_];

  int t = threadIdx.x;
  int wv = t >> 6;
  int lane = t & 63;
  int gr = blockIdx.x * 4 + wv;
  int s_local = gr >> 11;
  int row = gr & (N_ - 1);
  int slice = slice0 + s_local;

  const float* Srow = S + (size_t)s_local * N_ * N_ + (size_t)row * N_;

  // load 2048 logits: 32/lane; value (i) on lane l <-> col (i>>2)*256 + l*4 + (i&3)
  float x[32];
  #pragma unroll
  for (int i = 0; i < 8; ++i) {
    float4 v = *(const float4*)(Srow + i * 256 + lane * 4);
    x[i*4+0] = v.x; x[i*4+1] = v.y; x[i*4+2] = v.z; x[i*4+3] = v.w;
  }
  // order-preserving float -> uint
  unsigned u[32];
  #pragma unroll
  for (int i = 0; i < 32; ++i) {
    unsigned bits = __float_as_uint(x[i]);
    u[i] = bits ^ ((unsigned)(((int)bits) >> 31) | 0x80000000u);
  }

  // radix select: max thr with count(u >= thr) >= TOPK == 100th largest
  unsigned thr = 0u;
  for (int bit = 31; bit >= 0; --bit) {
    unsigned cand = thr | (1u << bit);
    int cnt = 0;
    #pragma unroll
    for (int i = 0; i < 32; ++i) {
      unsigned long long m = __ballot(u[i] >= cand);
      cnt += __popcll(m);
    }
    if (cnt >= TOPK_) thr = cand;
  }

  // row max
  float mx = -1e30f;
  #pragma unroll
  for (int i = 0; i < 32; ++i) mx = fmaxf(mx, x[i]);
  #pragma unroll
  for (int off = 32; off >= 1; off >>= 1) mx = fmaxf(mx, __shfl_xor(mx, off));

  // exp over kept (store back into x), sum
  float s = 0.f;
  #pragma unroll
  for (int i = 0; i < 32; ++i) {
    bool kp = (u[i] >= thr);
    float ev = kp ? __expf(x[i] - mx) : 0.f;
    x[i] = ev;
    s += ev;
  }
  #pragma unroll
  for (int off = 32; off >= 1; off >>= 1) s += __shfl_xor(s, off);
  float inv = 1.f / s;

  // ballot-compaction (deterministic order)
  int base = 0;
  #pragma unroll
  for (int i = 0; i < 32; ++i) {
    bool kp = (u[i] >= thr);
    unsigned long long m = __ballot(kp);
    if (kp) {
      int pos = base + mbcnt64(m);
      if (pos < CAP_) {
        wL[wv][pos] = x[i] * inv;
        iL[wv][pos] = (unsigned short)((i >> 2) * 256 + lane * 4 + (i & 3));
      }
    }
    base += __popcll(m);
  }
  int total = base < CAP_ ? base : CAP_;

  // gather-PV: lane = output dim d; 4 independent accumulators
  const float* Vs = vh + (size_t)slice * N_ * D_;
  float a0 = 0.f, a1 = 0.f, a2 = 0.f, a3 = 0.f;
  int e = 0;
  for (; e + 4 <= total; e += 4) {
    float w0 = wL[wv][e+0], w1 = wL[wv][e+1], w2 = wL[wv][e+2], w3 = wL[wv][e+3];
    int j0 = iL[wv][e+0], j1 = iL[wv][e+1], j2 = iL[wv][e+2], j3 = iL[wv][e+3];
    a0 = fmaf(w0, Vs[(size_t)j0 * D_ + lane], a0);
    a1 = fmaf(w1, Vs[(size_t)j1 * D_ + lane], a1);
    a2 = fmaf(w2, Vs[(size_t)j2 * D_ + lane], a2);
    a3 = fmaf(w3, Vs[(size_t)j3 * D_ + lane], a3);
  }
  for (; e < total; ++e)
    a0 = fmaf(wL[wv][e], Vs[(size_t)iL[wv][e] * D_ + lane], a0);
  float acc = (a0 + a1) + (a2 + a3);

  int b = slice >> 3;
  int h = slice & 7;
  outp[((size_t)(b * N_ + row)) * C_ + h * D_ + lane] = acc;
}

extern "C" void kernel_launch(void* const* d_in, const int* in_sizes, int n_in,
                              void* d_out, int out_size, void* d_ws, size_t ws_size,
                              hipStream_t stream) {
  const float* q  = (const float*)d_in[0];
  const float* k  = (const float*)d_in[1];
  const float* v  = (const float*)d_in[2];
  const float* Wq = (const float*)d_in[3];
  const float* bq = (const float*)d_in[4];
  const float* Wk = (const float*)d_in[5];
  const float* bk = (const float*)d_in[6];
  const float* Wv = (const float*)d_in[7];
  const float* bv = (const float*)d_in[8];
  const float* Wp = (const float*)d_in[9];
  const float* bp = (const float*)d_in[10];

  const size_t NB = (size_t)B_ * H_ * N_ * D_;   // 2,097,152 floats
  float* qh  = (float*)d_ws;
  float* kh  = qh + NB;
  float* vh  = kh + NB;
  float* pre = vh + NB;
  float* S   = pre + NB;

  // ns=4 keeps the S chunk (67 MB) L3-resident
  size_t fixedBytes = 4 * NB * sizeof(float);
  size_t sliceBytes = (size_t)N_ * N_ * sizeof(float);
  int ns = 1;
  if (ws_size > fixedBytes + sliceBytes) {
    size_t a = (ws_size - fixedBytes) / sliceBytes;
    ns = (a > 4) ? 4 : (int)a;
  }

  dim3 blk(256);

  proj3<<<dim3(BN_/128, C_/128, 3), blk, 0, stream>>>(
      q, k, v, Wq, Wk, Wv, bq, bk, bv, qh, kh, vh, C_, 1);

  for (int s0 = 0; s0 < B_ * H_; s0 += ns) {
    int cur = (B_ * H_ - s0) < ns ? (B_ * H_ - s0) : ns;
    qk128<<<dim3(N_/128, N_/128, cur), blk, 0, stream>>>(qh, kh, S, s0);
    topk_softmax_pv<<<dim3(cur * (N_/4)), blk, 0, stream>>>(S, vh, pre, s0);
  }

  proj3<<<dim3(BN_/128, C_/128, 1), blk, 0, stream>>>(
      pre, pre, pre, Wp, Wp, Wp, bp, bp, bp,
      (float*)d_out, (float*)d_out, (float*)d_out, C_, 0);
}

// Round 6
// 470.555 us; speedup vs baseline: 1.1665x; 1.1561x over previous
//
#include <hip/hip_runtime.h>
#include <stdint.h>

#define B_ 2
#define N_ 2048
#define C_ 512
#define H_ 8
#define D_ 64
#define TOPK_ 100
#define BN_ (B_*N_)
#define CAP_ 512

__device__ __forceinline__ int mbcnt64(unsigned long long m) {
  return __builtin_amdgcn_mbcnt_hi((unsigned)(m >> 32),
         __builtin_amdgcn_mbcnt_lo((unsigned)m, 0u));
}

// ---- 64x64-tile f32 GEMM: O = X @ W^T + bias ----
// NUMERICS CONTRACT: per output element, strictly k-ascending single-acc fmaf
// chain (k=0..511). This is bit-identical to the r1/r2 passing runs; do NOT
// split k or reorder the accumulation — the top-k kept set depends on it.
// scatter=1: head layout O[((b*H+h)*N+n)*64+d], h == blockIdx.y (64-wide tile).
__global__ __launch_bounds__(256)
void gemm64(const float* __restrict__ X0, const float* __restrict__ X1,
            const float* __restrict__ X2,
            const float* __restrict__ W0, const float* __restrict__ W1,
            const float* __restrict__ W2,
            const float* __restrict__ b0, const float* __restrict__ b1,
            const float* __restrict__ b2,
            float* __restrict__ O0, float* __restrict__ O1,
            float* __restrict__ O2, int scatter)
{
  int z = blockIdx.z;
  const float* X = (z == 0) ? X0 : ((z == 1) ? X1 : X2);
  const float* W = (z == 0) ? W0 : ((z == 1) ? W1 : W2);
  const float* bs = (z == 0) ? b0 : ((z == 1) ? b1 : b2);
  float* O = (z == 0) ? O0 : ((z == 1) ? O1 : O2);

  __shared__ float Xs[32][68];   // [k][m]
  __shared__ float Ws[32][68];   // [k][c]

  int t = threadIdx.x;
  int tr = t >> 4, tc = t & 15;
  int m0 = blockIdx.x * 64, c0 = blockIdx.y * 64;

  float acc[4][4] = {};

  for (int k0 = 0; k0 < C_; k0 += 32) {
    #pragma unroll
    for (int j2 = 0; j2 < 2; ++j2) {
      int fid = t + j2 * 256;      // 0..511
      int row = fid >> 3;          // 0..63 (8 lanes/row -> 128B coalesced)
      int dk  = (fid & 7) << 2;    // 0..28
      float4 xv = *(const float4*)(X + (size_t)(m0 + row) * C_ + k0 + dk);
      Xs[dk+0][row] = xv.x; Xs[dk+1][row] = xv.y; Xs[dk+2][row] = xv.z; Xs[dk+3][row] = xv.w;
      float4 wv = *(const float4*)(W + (size_t)(c0 + row) * C_ + k0 + dk);
      Ws[dk+0][row] = wv.x; Ws[dk+1][row] = wv.y; Ws[dk+2][row] = wv.z; Ws[dk+3][row] = wv.w;
    }
    __syncthreads();
    #pragma unroll
    for (int k = 0; k < 32; ++k) {
      float4 a = *(const float4*)&Xs[k][tr << 2];
      float4 b = *(const float4*)&Ws[k][tc << 2];
      float ar[4] = {a.x, a.y, a.z, a.w};
      float br[4] = {b.x, b.y, b.z, b.w};
      #pragma unroll
      for (int i = 0; i < 4; ++i)
        #pragma unroll
        for (int j = 0; j < 4; ++j)
          acc[i][j] = fmaf(ar[i], br[j], acc[i][j]);
    }
    __syncthreads();
  }

  float bv[4];
  #pragma unroll
  for (int j = 0; j < 4; ++j) bv[j] = bs[c0 + (tc << 2) + j];

  #pragma unroll
  for (int i = 0; i < 4; ++i) {
    float4 o = make_float4(acc[i][0] + bv[0], acc[i][1] + bv[1],
                           acc[i][2] + bv[2], acc[i][3] + bv[3]);
    int m = m0 + (tr << 2) + i;
    if (scatter) {
      int bb = m >> 11;            // /N_
      int tok = m & (N_ - 1);
      int h = blockIdx.y;          // c0>>6
      *(float4*)(O + (((size_t)(bb * H_ + h) * N_) + tok) * D_ + (tc << 2)) = o;
    } else {
      *(float4*)(O + (size_t)m * C_ + c0 + (tc << 2)) = o;
    }
  }
}

// ---- QK^T: S[r][m] = 0.125 * dot(qh[row0+r], kh[m]); same f32 fmaf contract ----
__global__ __launch_bounds__(256)
void qk64(const float* __restrict__ qh, const float* __restrict__ kh,
          float* __restrict__ S, int slice0, int row0, int Rrows)
{
  int z = blockIdx.z;
  int slice = slice0 + z;
  const float* Q = qh + (size_t)slice * N_ * D_;
  const float* K = kh + (size_t)slice * N_ * D_;
  float* Sp = S + (size_t)z * Rrows * N_;

  __shared__ float Qs[32][68];   // [k][n]
  __shared__ float Ks[32][68];   // [k][m]

  int t = threadIdx.x;
  int tr = t >> 4, tc = t & 15;
  int n0 = blockIdx.x * 64, m0 = blockIdx.y * 64;

  float acc[4][4] = {};

  #pragma unroll
  for (int k0 = 0; k0 < D_; k0 += 32) {
    #pragma unroll
    for (int j2 = 0; j2 < 2; ++j2) {
      int fid = t + j2 * 256;
      int row = fid >> 3;
      int dk  = (fid & 7) << 2;
      float4 qv = *(const float4*)(Q + (size_t)(row0 + n0 + row) * D_ + k0 + dk);
      Qs[dk+0][row] = qv.x; Qs[dk+1][row] = qv.y; Qs[dk+2][row] = qv.z; Qs[dk+3][row] = qv.w;
      float4 kv = *(const float4*)(K + (size_t)(m0 + row) * D_ + k0 + dk);
      Ks[dk+0][row] = kv.x; Ks[dk+1][row] = kv.y; Ks[dk+2][row] = kv.z; Ks[dk+3][row] = kv.w;
    }
    __syncthreads();
    #pragma unroll
    for (int k = 0; k < 32; ++k) {
      float4 a = *(const float4*)&Qs[k][tr << 2];
      float4 b = *(const float4*)&Ks[k][tc << 2];
      float ar[4] = {a.x, a.y, a.z, a.w};
      float br[4] = {b.x, b.y, b.z, b.w};
      #pragma unroll
      for (int i = 0; i < 4; ++i)
        #pragma unroll
        for (int j = 0; j < 4; ++j)
          acc[i][j] = fmaf(ar[i], br[j], acc[i][j]);
    }
    __syncthreads();
  }

  const float scale = 0.125f;  // D^-0.5
  #pragma unroll
  for (int i = 0; i < 4; ++i) {
    float4 o = make_float4(acc[i][0] * scale, acc[i][1] * scale,
                           acc[i][2] * scale, acc[i][3] * scale);
    *(float4*)(Sp + (size_t)(n0 + (tr << 2) + i) * N_ + m0 + (tc << 2)) = o;
  }
}

// ---- one wave per row: exact radix-select of 100th largest -> softmax over
// kept -> compaction -> gather-PV ----
__global__ __launch_bounds__(256)
void topk_softmax_pv(const float* __restrict__ S, const float* __restrict__ vh,
                     float* __restrict__ outp, int slice0, int row0, int log2R)
{
  __shared__ float wL[4][CAP_];
  __shared__ unsigned short iL[4][CAP_];

  int t = threadIdx.x;
  int wv = t >> 6;
  int lane = t & 63;
  int gr = blockIdx.x * 4 + wv;
  int s_local = gr >> log2R;
  int rrow = gr & ((1 << log2R) - 1);
  int slice = slice0 + s_local;
  int row = row0 + rrow;

  const float* Srow = S + ((size_t)gr) * N_;

  float x[32];
  #pragma unroll
  for (int i = 0; i < 8; ++i) {
    float4 v = *(const float4*)(Srow + i * 256 + lane * 4);
    x[i*4+0] = v.x; x[i*4+1] = v.y; x[i*4+2] = v.z; x[i*4+3] = v.w;
  }
  unsigned u[32];
  #pragma unroll
  for (int i = 0; i < 32; ++i) {
    unsigned bits = __float_as_uint(x[i]);
    u[i] = bits ^ ((unsigned)(((int)bits) >> 31) | 0x80000000u);
  }

  // exact radix select: max thr with count(u>=thr) >= TOPK == 100th largest.
  // Early exit when cnt==TOPK is exact: the kept SET {u>=final_thr} equals
  // {u>=cand} at that point (any element between cand and the top-K min would
  // contradict cnt==K).
  unsigned thr = 0u;
  for (int bit = 31; bit >= 0; --bit) {
    unsigned cand = thr | (1u << bit);
    int cnt = 0;
    #pragma unroll
    for (int i = 0; i < 32; ++i) {
      unsigned long long m = __ballot(u[i] >= cand);
      cnt += __popcll(m);
    }
    if (cnt >= TOPK_) {
      thr = cand;
      if (cnt == TOPK_) break;   // wave-uniform
    }
  }

  float mx = -1e30f;
  #pragma unroll
  for (int i = 0; i < 32; ++i) mx = fmaxf(mx, x[i]);
  #pragma unroll
  for (int off = 32; off >= 1; off >>= 1) mx = fmaxf(mx, __shfl_xor(mx, off));

  float s = 0.f;
  #pragma unroll
  for (int i = 0; i < 32; ++i) {
    bool kp = (u[i] >= thr);
    float ev = kp ? __expf(x[i] - mx) : 0.f;
    x[i] = ev;
    s += ev;
  }
  #pragma unroll
  for (int off = 32; off >= 1; off >>= 1) s += __shfl_xor(s, off);
  float inv = 1.f / s;

  int base = 0;
  #pragma unroll
  for (int i = 0; i < 32; ++i) {
    bool kp = (u[i] >= thr);
    unsigned long long m = __ballot(kp);
    if (kp) {
      int pos = base + mbcnt64(m);
      if (pos < CAP_) {
        wL[wv][pos] = x[i] * inv;
        iL[wv][pos] = (unsigned short)((i >> 2) * 256 + lane * 4 + (i & 3));
      }
    }
    base += __popcll(m);
  }
  int total = base < CAP_ ? base : CAP_;

  const float* Vs = vh + (size_t)slice * N_ * D_;
  float a0 = 0.f, a1 = 0.f, a2 = 0.f, a3 = 0.f;
  int e = 0;
  for (; e + 4 <= total; e += 4) {
    float w0 = wL[wv][e+0], w1 = wL[wv][e+1], w2 = wL[wv][e+2], w3 = wL[wv][e+3];
    int j0 = iL[wv][e+0], j1 = iL[wv][e+1], j2 = iL[wv][e+2], j3 = iL[wv][e+3];
    a0 = fmaf(w0, Vs[(size_t)j0 * D_ + lane], a0);
    a1 = fmaf(w1, Vs[(size_t)j1 * D_ + lane], a1);
    a2 = fmaf(w2, Vs[(size_t)j2 * D_ + lane], a2);
    a3 = fmaf(w3, Vs[(size_t)j3 * D_ + lane], a3);
  }
  for (; e < total; ++e)
    a0 = fmaf(wL[wv][e], Vs[(size_t)iL[wv][e] * D_ + lane], a0);
  float acc = (a0 + a1) + (a2 + a3);

  int b = slice >> 3;
  int h = slice & 7;
  outp[((size_t)(b * N_ + row)) * C_ + h * D_ + lane] = acc;
}

extern "C" void kernel_launch(void* const* d_in, const int* in_sizes, int n_in,
                              void* d_out, int out_size, void* d_ws, size_t ws_size,
                              hipStream_t stream) {
  const float* q  = (const float*)d_in[0];
  const float* k  = (const float*)d_in[1];
  const float* v  = (const float*)d_in[2];
  const float* Wq = (const float*)d_in[3];
  const float* bq = (const float*)d_in[4];
  const float* Wk = (const float*)d_in[5];
  const float* bk = (const float*)d_in[6];
  const float* Wv = (const float*)d_in[7];
  const float* bv = (const float*)d_in[8];
  const float* Wp = (const float*)d_in[9];
  const float* bp = (const float*)d_in[10];

  const size_t NB = (size_t)B_ * H_ * N_ * D_;   // 2,097,152 floats
  float* qh  = (float*)d_ws;
  float* kh  = qh + NB;
  float* vh  = kh + NB;
  float* pre = vh + NB;
  float* S   = pre + NB;

  size_t fixedB = 4 * NB * sizeof(float);              // 32 MB
  size_t sliceB = (size_t)N_ * N_ * sizeof(float);     // 16.78 MB
  size_t avail = (ws_size > fixedB) ? ws_size - fixedB : 0;

  int ns = 1, R = 2048;
  if      (avail >= 4 * sliceB) { ns = 4; R = 2048; }
  else if (avail >= 2 * sliceB) { ns = 2; R = 2048; }
  else if (avail >= 1 * sliceB) { ns = 1; R = 2048; }
  else if (avail >= sliceB / 2) { ns = 1; R = 1024; }
  else                          { ns = 1; R = 512;  }
  int log2R = (R == 2048) ? 11 : ((R == 1024) ? 10 : 9);

  dim3 blk(256);

  // Q/K/V projections, head-scatter output
  gemm64<<<dim3(BN_/64, C_/64, 3), blk, 0, stream>>>(
      q, k, v, Wq, Wk, Wv, bq, bk, bv, qh, kh, vh, 1);

  for (int s0 = 0; s0 < B_ * H_; s0 += ns) {
    int cur = (B_ * H_ - s0) < ns ? (B_ * H_ - s0) : ns;
    for (int r0 = 0; r0 < N_; r0 += R) {
      qk64<<<dim3(R/64, N_/64, cur), blk, 0, stream>>>(qh, kh, S, s0, r0, R);
      topk_softmax_pv<<<dim3(cur * (R/4)), blk, 0, stream>>>(S, vh, pre, s0, r0, log2R);
    }
  }

  // final projection -> d_out
  gemm64<<<dim3(BN_/64, C_/64, 1), blk, 0, stream>>>(
      pre, pre, pre, Wp, Wp, Wp, bp, bp, bp,
      (float*)d_out, (float*)d_out, (float*)d_out, 0);
}

// Round 7
// 449.326 us; speedup vs baseline: 1.2217x; 1.0472x over previous
//
#include <hip/hip_runtime.h>
#include <stdint.h>

#define B_ 2
#define N_ 2048
#define C_ 512
#define H_ 8
#define D_ 64
#define TOPK_ 100
#define BN_ (B_*N_)
#define CAP_ 512

typedef __attribute__((ext_vector_type(8))) short s16x8;
typedef __attribute__((ext_vector_type(4))) float f32x4;
typedef unsigned int uint;

__device__ __forceinline__ int mbcnt64(unsigned long long m) {
  return __builtin_amdgcn_mbcnt_hi((unsigned)(m >> 32),
         __builtin_amdgcn_mbcnt_lo((unsigned)m, 0u));
}
__device__ __forceinline__ unsigned short bf16rn(float x) {
  unsigned u = __float_as_uint(x);
  unsigned r = (u + 0x7fffu + ((u >> 16) & 1u)) >> 16;
  return (unsigned short)r;
}
__device__ __forceinline__ float bf16f(unsigned short h) {
  return __uint_as_float(((unsigned)h) << 16);
}
__device__ __forceinline__ void split3(float x, unsigned short& h,
                                       unsigned short& m, unsigned short& l) {
  h = bf16rn(x);
  float r1 = x - bf16f(h);
  m = bf16rn(r1);
  float r2 = r1 - bf16f(m);
  l = bf16rn(r2);
}
#define SWZ(r, sl) (((sl) ^ (((r) >> 1) & 3)) << 3)
#define MFMA_BF16(a, b, c) __builtin_amdgcn_mfma_f32_16x16x32_bf16(a, b, c, 0, 0, 0)
#define SIX_PASS(acc, ah, am, al, bh, bm, bl) \
  do { \
    acc = MFMA_BF16(ah, bl, acc); \
    acc = MFMA_BF16(am, bm, acc); \
    acc = MFMA_BF16(al, bh, acc); \
    acc = MFMA_BF16(ah, bm, acc); \
    acc = MFMA_BF16(am, bh, acc); \
    acc = MFMA_BF16(ah, bh, acc); \
  } while (0)

// ---- split weights (Wv, Wp) into 3 bf16 planes each ----
__global__ __launch_bounds__(256)
void wsplit(const float* __restrict__ W0, const float* __restrict__ W1,
            unsigned short* __restrict__ Wsp)
{
  int z = blockIdx.y;
  const float* W = (z == 0) ? W0 : W1;
  const size_t WN = (size_t)C_ * C_;
  unsigned short* Wh = Wsp + (size_t)z * 3 * WN;
  unsigned short* Wm = Wh + WN;
  unsigned short* Wl = Wh + 2 * WN;
  int i = blockIdx.x * 256 + threadIdx.x;
  unsigned short h, m, l;
  split3(W[i], h, m, l);
  Wh[i] = h; Wm[i] = m; Wl[i] = l;
}

// ---- EXACT f32 64x64 GEMM for qh/kh only ----
// NUMERICS CONTRACT: per output, strictly k-ascending single-acc fmaf chain
// (k=0..511), bias added once at the end. Bit-identical to the passing r2/r6
// runs. The top-k kept set depends on this — do not reorder.
__global__ __launch_bounds__(256)
void gemm64(const float* __restrict__ X0, const float* __restrict__ X1,
            const float* __restrict__ W0, const float* __restrict__ W1,
            const float* __restrict__ b0, const float* __restrict__ b1,
            float* __restrict__ O0, float* __restrict__ O1)
{
  int z = blockIdx.z;
  const float* X = (z == 0) ? X0 : X1;
  const float* W = (z == 0) ? W0 : W1;
  const float* bs = (z == 0) ? b0 : b1;
  float* O = (z == 0) ? O0 : O1;

  __shared__ float Xs[32][68];
  __shared__ float Ws[32][68];

  int t = threadIdx.x;
  int tr = t >> 4, tc = t & 15;
  int m0 = blockIdx.x * 64, c0 = blockIdx.y * 64;

  float acc[4][4] = {};

  for (int k0 = 0; k0 < C_; k0 += 32) {
    #pragma unroll
    for (int j2 = 0; j2 < 2; ++j2) {
      int fid = t + j2 * 256;
      int row = fid >> 3;
      int dk  = (fid & 7) << 2;
      float4 xv = *(const float4*)(X + (size_t)(m0 + row) * C_ + k0 + dk);
      Xs[dk+0][row] = xv.x; Xs[dk+1][row] = xv.y; Xs[dk+2][row] = xv.z; Xs[dk+3][row] = xv.w;
      float4 wv = *(const float4*)(W + (size_t)(c0 + row) * C_ + k0 + dk);
      Ws[dk+0][row] = wv.x; Ws[dk+1][row] = wv.y; Ws[dk+2][row] = wv.z; Ws[dk+3][row] = wv.w;
    }
    __syncthreads();
    #pragma unroll
    for (int k = 0; k < 32; ++k) {
      float4 a = *(const float4*)&Xs[k][tr << 2];
      float4 b = *(const float4*)&Ws[k][tc << 2];
      float ar[4] = {a.x, a.y, a.z, a.w};
      float br[4] = {b.x, b.y, b.z, b.w};
      #pragma unroll
      for (int i = 0; i < 4; ++i)
        #pragma unroll
        for (int j = 0; j < 4; ++j)
          acc[i][j] = fmaf(ar[i], br[j], acc[i][j]);
    }
    __syncthreads();
  }

  float bv[4];
  #pragma unroll
  for (int j = 0; j < 4; ++j) bv[j] = bs[c0 + (tc << 2) + j];

  #pragma unroll
  for (int i = 0; i < 4; ++i) {
    float4 o = make_float4(acc[i][0] + bv[0], acc[i][1] + bv[1],
                           acc[i][2] + bv[2], acc[i][3] + bv[3]);
    int m = m0 + (tr << 2) + i;
    int bb = m >> 11;
    int tok = m & (N_ - 1);
    int h = blockIdx.y;
    *(float4*)(O + (((size_t)(bb * H_ + h) * N_) + tok) * D_ + (tc << 2)) = o;
  }
}

// ---- bf16x3 6-pass MFMA GEMM for vh and final proj (post-select paths) ----
__global__ __launch_bounds__(256)
void gemm_mfma(const float* __restrict__ A,
               const unsigned short* __restrict__ Wplanes,
               const float* __restrict__ bias,
               float* __restrict__ O, int scatter)
{
  const size_t WN = (size_t)C_ * C_;
  const unsigned short* Wh = Wplanes;
  const unsigned short* Wm = Wplanes + WN;
  const unsigned short* Wl = Wplanes + 2 * WN;

  __shared__ unsigned short Ah[128][32], Am[128][32], Al[128][32];
  __shared__ unsigned short Bh[128][32], Bm[128][32], Bl[128][32];

  int t = threadIdx.x;
  int l = t & 63, wv = t >> 6;
  int wm = wv >> 1, wn = wv & 1;
  int m0 = blockIdx.x * 128, n0 = blockIdx.y * 128;

  f32x4 acc[4][4];
  #pragma unroll
  for (int i = 0; i < 4; ++i)
    #pragma unroll
    for (int j = 0; j < 4; ++j) acc[i][j] = (f32x4){0.f,0.f,0.f,0.f};

  for (int k0 = 0; k0 < C_; k0 += 32) {
    #pragma unroll
    for (int sj = 0; sj < 2; ++sj) {
      int s = t + sj * 256;
      int r = s >> 2, sl = s & 3, c = sl << 3;
      int co = SWZ(r, sl);
      const float* src = A + (size_t)(m0 + r) * C_ + k0 + c;
      float4 x0 = *(const float4*)src;
      float4 x1 = *(const float4*)(src + 4);
      float xs[8] = {x0.x,x0.y,x0.z,x0.w,x1.x,x1.y,x1.z,x1.w};
      unsigned short hv[8], mv[8], lv[8];
      #pragma unroll
      for (int j = 0; j < 8; ++j) split3(xs[j], hv[j], mv[j], lv[j]);
      *(s16x8*)&Ah[r][co] = *(s16x8*)hv;
      *(s16x8*)&Am[r][co] = *(s16x8*)mv;
      *(s16x8*)&Al[r][co] = *(s16x8*)lv;
      size_t boff = (size_t)(n0 + r) * C_ + k0 + c;
      *(s16x8*)&Bh[r][co] = *(const s16x8*)&Wh[boff];
      *(s16x8*)&Bm[r][co] = *(const s16x8*)&Wm[boff];
      *(s16x8*)&Bl[r][co] = *(const s16x8*)&Wl[boff];
    }
    __syncthreads();

    int lr = l & 15, s0 = l >> 4;
    s16x8 ah[4], am[4], al[4];
    #pragma unroll
    for (int mi = 0; mi < 4; ++mi) {
      int R = wm*64 + mi*16 + lr;
      int co = SWZ(R, s0);
      ah[mi] = *(const s16x8*)&Ah[R][co];
      am[mi] = *(const s16x8*)&Am[R][co];
      al[mi] = *(const s16x8*)&Al[R][co];
    }
    #pragma unroll
    for (int nj = 0; nj < 4; ++nj) {
      int Rb = wn*64 + nj*16 + lr;
      int co = SWZ(Rb, s0);
      s16x8 bh = *(const s16x8*)&Bh[Rb][co];
      s16x8 bm = *(const s16x8*)&Bm[Rb][co];
      s16x8 bl = *(const s16x8*)&Bl[Rb][co];
      #pragma unroll
      for (int mi = 0; mi < 4; ++mi)
        SIX_PASS(acc[mi][nj], ah[mi], am[mi], al[mi], bh, bm, bl);
    }
    __syncthreads();
  }

  int lr = l & 15, lq = l >> 4;
  #pragma unroll
  for (int mi = 0; mi < 4; ++mi) {
    #pragma unroll
    for (int nj = 0; nj < 4; ++nj) {
      #pragma unroll
      for (int r = 0; r < 4; ++r) {
        int m = m0 + wm*64 + mi*16 + lq*4 + r;
        int c = n0 + wn*64 + nj*16 + lr;
        float y = acc[mi][nj][r] + bias[c];
        if (scatter) {
          int bb = m >> 11, tok = m & (N_ - 1);
          int hh = c >> 6, d = c & 63;
          O[(((size_t)(bb * H_ + hh) * N_) + tok) * D_ + d] = y;
        } else {
          O[(size_t)m * C_ + c] = y;
        }
      }
    }
  }
}

// ---- EXACT f32 QK^T: 128x128 tile, 8x8 micro (two 4-col groups 64 apart).
// Per-output chain: fmaf k=0..63 ascending, *0.125 at end — bit-identical
// to r6's qk64. ----
__global__ __launch_bounds__(256)
void qk128(const float* __restrict__ qh, const float* __restrict__ kh,
           float* __restrict__ S, int slice0, int row0, int Rrows)
{
  int z = blockIdx.z;
  int slice = slice0 + z;
  const float* Q = qh + (size_t)slice * N_ * D_;
  const float* K = kh + (size_t)slice * N_ * D_;
  float* Sp = S + (size_t)z * Rrows * N_;

  __shared__ float Qs[32][132];
  __shared__ float Ks[32][132];

  int t = threadIdx.x;
  int tr = t >> 4, tc = t & 15;
  int n0 = blockIdx.x * 128, m0 = blockIdx.y * 128;

  float acc[2][2][4][4] = {};

  #pragma unroll
  for (int k0 = 0; k0 < D_; k0 += 32) {
    #pragma unroll
    for (int jj = 0; jj < 4; ++jj) {
      int fid = t + jj * 256;
      int row = fid >> 3;
      int dk  = (fid & 7) << 2;
      float4 qv = *(const float4*)(Q + (size_t)(row0 + n0 + row) * D_ + k0 + dk);
      Qs[dk+0][row] = qv.x; Qs[dk+1][row] = qv.y; Qs[dk+2][row] = qv.z; Qs[dk+3][row] = qv.w;
      float4 kv = *(const float4*)(K + (size_t)(m0 + row) * D_ + k0 + dk);
      Ks[dk+0][row] = kv.x; Ks[dk+1][row] = kv.y; Ks[dk+2][row] = kv.z; Ks[dk+3][row] = kv.w;
    }
    __syncthreads();
    #pragma unroll
    for (int k = 0; k < 32; ++k) {
      float a[2][4], b[2][4];
      *(float4*)&a[0][0] = *(const float4*)&Qs[k][tr << 2];
      *(float4*)&a[1][0] = *(const float4*)&Qs[k][64 + (tr << 2)];
      *(float4*)&b[0][0] = *(const float4*)&Ks[k][tc << 2];
      *(float4*)&b[1][0] = *(const float4*)&Ks[k][64 + (tc << 2)];
      #pragma unroll
      for (int ia = 0; ia < 2; ++ia)
        #pragma unroll
        for (int ib = 0; ib < 2; ++ib)
          #pragma unroll
          for (int i = 0; i < 4; ++i)
            #pragma unroll
            for (int j = 0; j < 4; ++j)
              acc[ia][ib][i][j] = fmaf(a[ia][i], b[ib][j], acc[ia][ib][i][j]);
    }
    __syncthreads();
  }

  const float scale = 0.125f;
  #pragma unroll
  for (int ia = 0; ia < 2; ++ia)
    #pragma unroll
    for (int i = 0; i < 4; ++i) {
      int n = n0 + ia*64 + (tr << 2) + i;
      #pragma unroll
      for (int ib = 0; ib < 2; ++ib) {
        float4 o = make_float4(acc[ia][ib][i][0] * scale, acc[ia][ib][i][1] * scale,
                               acc[ia][ib][i][2] * scale, acc[ia][ib][i][3] * scale);
        *(float4*)(Sp + (size_t)n * N_ + m0 + ib*64 + (tc << 2)) = o;
      }
    }
}

// ---- one wave per row: exact radix-select -> softmax over kept -> gather-PV ----
__global__ __launch_bounds__(256)
void topk_softmax_pv(const float* __restrict__ S, const float* __restrict__ vh,
                     float* __restrict__ outp, int slice0, int row0, int log2R)
{
  __shared__ float wL[4][CAP_];
  __shared__ unsigned short iL[4][CAP_];

  int t = threadIdx.x;
  int wv = t >> 6;
  int lane = t & 63;
  int gr = blockIdx.x * 4 + wv;
  int s_local = gr >> log2R;
  int rrow = gr & ((1 << log2R) - 1);
  int slice = slice0 + s_local;
  int row = row0 + rrow;

  const float* Srow = S + ((size_t)gr) * N_;

  float x[32];
  #pragma unroll
  for (int i = 0; i < 8; ++i) {
    float4 v = *(const float4*)(Srow + i * 256 + lane * 4);
    x[i*4+0] = v.x; x[i*4+1] = v.y; x[i*4+2] = v.z; x[i*4+3] = v.w;
  }
  unsigned u[32];
  #pragma unroll
  for (int i = 0; i < 32; ++i) {
    unsigned bits = __float_as_uint(x[i]);
    u[i] = bits ^ ((unsigned)(((int)bits) >> 31) | 0x80000000u);
  }

  unsigned thr = 0u;
  for (int bit = 31; bit >= 0; --bit) {
    unsigned cand = thr | (1u << bit);
    int cnt = 0;
    #pragma unroll
    for (int i = 0; i < 32; ++i) {
      unsigned long long m = __ballot(u[i] >= cand);
      cnt += __popcll(m);
    }
    if (cnt >= TOPK_) {
      thr = cand;
      if (cnt == TOPK_) break;   // exact: kept set {u>=cand} is final
    }
  }

  float mx = -1e30f;
  #pragma unroll
  for (int i = 0; i < 32; ++i) mx = fmaxf(mx, x[i]);
  #pragma unroll
  for (int off = 32; off >= 1; off >>= 1) mx = fmaxf(mx, __shfl_xor(mx, off));

  float s = 0.f;
  #pragma unroll
  for (int i = 0; i < 32; ++i) {
    bool kp = (u[i] >= thr);
    float ev = kp ? __expf(x[i] - mx) : 0.f;
    x[i] = ev;
    s += ev;
  }
  #pragma unroll
  for (int off = 32; off >= 1; off >>= 1) s += __shfl_xor(s, off);
  float inv = 1.f / s;

  int base = 0;
  #pragma unroll
  for (int i = 0; i < 32; ++i) {
    bool kp = (u[i] >= thr);
    unsigned long long m = __ballot(kp);
    if (kp) {
      int pos = base + mbcnt64(m);
      if (pos < CAP_) {
        wL[wv][pos] = x[i] * inv;
        iL[wv][pos] = (unsigned short)((i >> 2) * 256 + lane * 4 + (i & 3));
      }
    }
    base += __popcll(m);
  }
  int total = base < CAP_ ? base : CAP_;

  // gather-PV, 8-deep ILP (post-select: reorder safe)
  const float* Vs = vh + (size_t)slice * N_ * D_;
  float a0=0.f,a1=0.f,a2=0.f,a3=0.f,a4=0.f,a5=0.f,a6=0.f,a7=0.f;
  int e = 0;
  for (; e + 8 <= total; e += 8) {
    float w0=wL[wv][e+0], w1=wL[wv][e+1], w2=wL[wv][e+2], w3=wL[wv][e+3];
    float w4=wL[wv][e+4], w5=wL[wv][e+5], w6=wL[wv][e+6], w7=wL[wv][e+7];
    int j0=iL[wv][e+0], j1=iL[wv][e+1], j2=iL[wv][e+2], j3=iL[wv][e+3];
    int j4=iL[wv][e+4], j5=iL[wv][e+5], j6=iL[wv][e+6], j7=iL[wv][e+7];
    float v0=Vs[(size_t)j0*D_+lane], v1=Vs[(size_t)j1*D_+lane];
    float v2=Vs[(size_t)j2*D_+lane], v3=Vs[(size_t)j3*D_+lane];
    float v4=Vs[(size_t)j4*D_+lane], v5=Vs[(size_t)j5*D_+lane];
    float v6=Vs[(size_t)j6*D_+lane], v7=Vs[(size_t)j7*D_+lane];
    a0 = fmaf(w0, v0, a0); a1 = fmaf(w1, v1, a1);
    a2 = fmaf(w2, v2, a2); a3 = fmaf(w3, v3, a3);
    a4 = fmaf(w4, v4, a4); a5 = fmaf(w5, v5, a5);
    a6 = fmaf(w6, v6, a6); a7 = fmaf(w7, v7, a7);
  }
  for (; e < total; ++e)
    a0 = fmaf(wL[wv][e], Vs[(size_t)iL[wv][e] * D_ + lane], a0);
  float acc = ((a0 + a1) + (a2 + a3)) + ((a4 + a5) + (a6 + a7));

  int b = slice >> 3;
  int h = slice & 7;
  outp[((size_t)(b * N_ + row)) * C_ + h * D_ + lane] = acc;
}

extern "C" void kernel_launch(void* const* d_in, const int* in_sizes, int n_in,
                              void* d_out, int out_size, void* d_ws, size_t ws_size,
                              hipStream_t stream) {
  const float* q  = (const float*)d_in[0];
  const float* k  = (const float*)d_in[1];
  const float* v  = (const float*)d_in[2];
  const float* Wq = (const float*)d_in[3];
  const float* bq = (const float*)d_in[4];
  const float* Wk = (const float*)d_in[5];
  const float* bk = (const float*)d_in[6];
  const float* Wv = (const float*)d_in[7];
  const float* bv = (const float*)d_in[8];
  const float* Wp = (const float*)d_in[9];
  const float* bp = (const float*)d_in[10];

  const size_t NB = (size_t)B_ * H_ * N_ * D_;   // 2,097,152 floats
  const size_t WN = (size_t)C_ * C_;
  float* qh  = (float*)d_ws;
  float* kh  = qh + NB;
  float* vh  = kh + NB;
  float* pre = vh + NB;
  unsigned short* Wsp = (unsigned short*)(pre + NB);   // 2 x 3 x WN u16
  float* S   = (float*)(Wsp + 2 * 3 * WN);

  size_t fixedB = 4 * NB * 4 + 2 * 3 * WN * 2;         // ~35.1 MB
  size_t sliceB = (size_t)N_ * N_ * 4;                 // 16.78 MB
  size_t avail = (ws_size > fixedB) ? ws_size - fixedB : 0;

  int ns = 1, R = 2048;
  if      (avail >= 4 * sliceB) { ns = 4; R = 2048; }
  else if (avail >= 2 * sliceB) { ns = 2; R = 2048; }
  else if (avail >= 1 * sliceB) { ns = 1; R = 2048; }
  else if (avail >= sliceB / 2) { ns = 1; R = 1024; }
  else                          { ns = 1; R = 512;  }
  int log2R = (R == 2048) ? 11 : ((R == 1024) ? 10 : 9);

  dim3 blk(256);

  // weight splits for the two MFMA GEMMs (Wv, Wp)
  wsplit<<<dim3(WN / 256, 2), blk, 0, stream>>>(Wv, Wp, Wsp);

  // q,k projections: EXACT f32 chain, head-scatter
  gemm64<<<dim3(BN_/64, C_/64, 2), blk, 0, stream>>>(
      q, k, Wq, Wk, bq, bk, qh, kh);

  // v projection: bf16x3 6-pass MFMA (post-select path), head-scatter
  gemm_mfma<<<dim3(BN_/128, C_/128), blk, 0, stream>>>(
      v, Wsp, bv, vh, 1);

  for (int s0 = 0; s0 < B_ * H_; s0 += ns) {
    int cur = (B_ * H_ - s0) < ns ? (B_ * H_ - s0) : ns;
    for (int r0 = 0; r0 < N_; r0 += R) {
      qk128<<<dim3(R/128, N_/128, cur), blk, 0, stream>>>(qh, kh, S, s0, r0, R);
      topk_softmax_pv<<<dim3(cur * (R/4)), blk, 0, stream>>>(S, vh, pre, s0, r0, log2R);
    }
  }

  // final projection: bf16x3 6-pass MFMA -> d_out
  gemm_mfma<<<dim3(BN_/128, C_/128), blk, 0, stream>>>(
      pre, Wsp + 3 * WN, bp, (float*)d_out, 0);
}